// Round 4
// baseline (183.653 us; speedup 1.0000x reference)
//
#include <hip/hip_runtime.h>
#include <math.h>

// PHOSA interaction loss, MI355X — gather-free formulation, spill-fixed.
// Part index lists are batch-independent: per-vertex part multiplicity
// (4-bit count x 8 parts packed in a u32) is built once; part statistics are
// computed in the SAME streaming pass as the batch sums.
// Round-4 change: __launch_bounds__(256, 4) on the stream kernel so the
// 72 per-thread accumulators live in VGPRs (round 3: 80 VGPRs -> scratch
// spills -> 190 us VALU-bound).
constexpr int B_   = 256;
constexpr int NS_  = 10475;
constexpr int NO_  = 65536;
constexpr int P_   = 8;
constexpr int KS_  = 1024;
constexpr int KO_  = 2048;
constexpr int NBLK_S = 4;    // blocks per batch, smpl stream
constexpr int NBLK_O = 16;   // blocks per batch, object stream
constexpr float EPS_ = 1e-9f;
constexpr float ZTH_ = 5.0f;

#define DEV_INLINE __device__ __forceinline__

DEV_INLINE float wredsum(float v) {
#pragma unroll
    for (int o = 32; o; o >>= 1) v += __shfl_down(v, o);
    return v;
}
DEV_INLINE float wredmin(float v) {
#pragma unroll
    for (int o = 32; o; o >>= 1) v = fminf(v, __shfl_down(v, o));
    return v;
}
DEV_INLINE float wredmax(float v) {
#pragma unroll
    for (int o = 32; o; o >>= 1) v = fmaxf(v, __shfl_down(v, o));
    return v;
}

// ---------------------------------------------------------------------------
// Kernel 1: scatter part multiplicities into per-vertex count tables.
// cnt[vertex] bits [4p, 4p+4) = number of times vertex appears in part p.
// ---------------------------------------------------------------------------
__global__ __launch_bounds__(256) void scatter_counts_kernel(
        const int* __restrict__ sidx, const int* __restrict__ oidx,
        unsigned* __restrict__ cntS, unsigned* __restrict__ cntO) {
    const int t = blockIdx.x * 256 + threadIdx.x;
    constexpr int TO = P_ * KO_;
    if (t < TO) {
        const int p = t / KO_;
        atomicAdd(&cntO[oidx[t]], 1u << (4 * p));
    } else if (t < TO + P_ * KS_) {
        const int u = t - TO;
        const int p = u / KS_;
        atomicAdd(&cntS[sidx[u]], 1u << (4 * p));
    }
}

// ---------------------------------------------------------------------------
// Kernel 2: fused stream. Blocks [0, B*NBLK_O) stream object, rest smpl.
// Per block: partial batch xyz sums (bitwise-identical order to round-1 path)
// + per-part {umin,umax,wmin,wmax,zmin,zmax,sx,sy,sz} partials.
// Partial layout per (b,blk): 72 floats, q = kind*8 + part.
// ---------------------------------------------------------------------------
__global__ __launch_bounds__(256, 4) void fused_stream_kernel(
        const float* __restrict__ obj, const float* __restrict__ smpl,
        const unsigned* __restrict__ cntO, const unsigned* __restrict__ cntS,
        const float* __restrict__ Ks,
        float* __restrict__ partO, float* __restrict__ sumO,
        float* __restrict__ partS, float* __restrict__ sumS) {
    int gid = blockIdx.x;
    const float* v; const unsigned* cnt; int N, NBLK, b, blk;
    float* part; float* sums;
    if (gid < B_ * NBLK_O) {
        v = obj; cnt = cntO; N = NO_; NBLK = NBLK_O;
        b = gid / NBLK_O; blk = gid % NBLK_O; part = partO; sums = sumO;
    } else {
        gid -= B_ * NBLK_O;
        v = smpl; cnt = cntS; N = NS_; NBLK = NBLK_S;
        b = gid / NBLK_S; blk = gid % NBLK_S; part = partS; sums = sumS;
    }
    const int chunk = (N + NBLK - 1) / NBLK;
    const int s0 = blk * chunk;
    const int e0 = min(N, s0 + chunk);
    const float* base = v + (size_t)b * N * 3;
    const float fx = Ks[b * 9 + 0];
    const float cx = Ks[b * 9 + 2];
    const float fy = Ks[b * 9 + 4];
    const float cy = Ks[b * 9 + 5];

    float sx = 0.f, sy = 0.f, sz = 0.f;
    float umin[8], umax[8], wmin[8], wmax[8], zmn[8], zmx[8], psx[8], psy[8], psz[8];
#pragma unroll
    for (int q = 0; q < 8; ++q) {
        umin[q] = INFINITY; umax[q] = -INFINITY;
        wmin[q] = INFINITY; wmax[q] = -INFINITY;
        zmn[q]  = INFINITY; zmx[q]  = -INFINITY;
        psx[q] = 0.f; psy[q] = 0.f; psz[q] = 0.f;
    }

    for (int i = s0 + (int)threadIdx.x; i < e0; i += 256) {
        const float* p = base + (size_t)i * 3;
        const float x = p[0], y = p[1], z = p[2];
        sx += x; sy += y; sz += z;
        const unsigned c = cnt[i];
        float u, w;
        {
#pragma clang fp contract(off)
            const float zd = z + EPS_;
            const float x_ = x / zd;
            const float y_ = (-y) / zd;
            u = fx * x_ + cx;
            w = 1.0f - (fy * y_ + cy);
            u = 2.0f * (u - 0.5f);
            w = 2.0f * (w - 0.5f);
        }
#pragma unroll
        for (int q = 0; q < 8; ++q) {
            const unsigned cq = (c >> (4 * q)) & 15u;
            const float fc = (float)cq;
            const bool a = cq != 0u;
            umin[q] = fminf(umin[q], a ? u :  INFINITY);
            umax[q] = fmaxf(umax[q], a ? u : -INFINITY);
            wmin[q] = fminf(wmin[q], a ? w :  INFINITY);
            wmax[q] = fmaxf(wmax[q], a ? w : -INFINITY);
            zmn[q]  = fminf(zmn[q],  a ? z :  INFINITY);
            zmx[q]  = fmaxf(zmx[q],  a ? z : -INFINITY);
            psx[q] = fmaf(fc, x, psx[q]);
            psy[q] = fmaf(fc, y, psy[q]);
            psz[q] = fmaf(fc, z, psz[q]);
        }
    }

    // wave reductions
    sx = wredsum(sx); sy = wredsum(sy); sz = wredsum(sz);
#pragma unroll
    for (int q = 0; q < 8; ++q) {
        umin[q] = wredmin(umin[q]); umax[q] = wredmax(umax[q]);
        wmin[q] = wredmin(wmin[q]); wmax[q] = wredmax(wmax[q]);
        zmn[q]  = wredmin(zmn[q]);  zmx[q]  = wredmax(zmx[q]);
        psx[q]  = wredsum(psx[q]);  psy[q]  = wredsum(psy[q]);
        psz[q]  = wredsum(psz[q]);
    }
    __shared__ float red[4][76];
    const int lane = threadIdx.x & 63, wv = threadIdx.x >> 6;
    if (lane == 0) {
        red[wv][0] = sx; red[wv][1] = sy; red[wv][2] = sz;
#pragma unroll
        for (int q = 0; q < 8; ++q) {
            red[wv][3 + 0 * 8 + q] = umin[q];
            red[wv][3 + 1 * 8 + q] = umax[q];
            red[wv][3 + 2 * 8 + q] = wmin[q];
            red[wv][3 + 3 * 8 + q] = wmax[q];
            red[wv][3 + 4 * 8 + q] = zmn[q];
            red[wv][3 + 5 * 8 + q] = zmx[q];
            red[wv][3 + 6 * 8 + q] = psx[q];
            red[wv][3 + 7 * 8 + q] = psy[q];
            red[wv][3 + 8 * 8 + q] = psz[q];
        }
    }
    __syncthreads();
    const int t = threadIdx.x;
    if (t < 75) {
        const float a0 = red[0][t], a1 = red[1][t], a2 = red[2][t], a3 = red[3][t];
        if (t < 3) {
            // same combine order as round-1 batch_sum -> loss_inter bitwise identical
            sums[((size_t)b * NBLK + blk) * 3 + t] = a0 + a1 + a2 + a3;
        } else {
            const int kind = (t - 3) >> 3;
            float r;
            if (kind == 0 || kind == 2 || kind == 4)
                r = fminf(fminf(a0, a1), fminf(a2, a3));
            else if (kind == 1 || kind == 3 || kind == 5)
                r = fmaxf(fmaxf(a0, a1), fmaxf(a2, a3));
            else
                r = a0 + a1 + a2 + a3;
            part[((size_t)b * NBLK + blk) * 72 + (t - 3)] = r;
        }
    }
}

// ---------------------------------------------------------------------------
// Kernel 3: per-batch finish — combine stream partials into 8x9 stats per
// tensor, then the 8x8 pair mask/mse. One block (64 thr) per batch.
// ---------------------------------------------------------------------------
__global__ __launch_bounds__(64) void finish_kernel(
        const float* __restrict__ partS, const float* __restrict__ partO,
        float* __restrict__ pairPartial) {
#pragma clang fp contract(off)
    const int b = blockIdx.x;
    const int t = threadIdx.x;
    __shared__ float sS[P_][9];
    __shared__ float sO[P_][9];
    for (int q = t; q < 72; q += 64) {
        const int kind = q >> 3, part = q & 7;
        const bool isMin = (kind == 0 || kind == 2 || kind == 4);
        const bool isMax = (kind == 1 || kind == 3 || kind == 5);
        {
            const float* po = partO + ((size_t)b * NBLK_O) * 72 + q;
            float acc = isMin ? INFINITY : (isMax ? -INFINITY : 0.f);
#pragma unroll
            for (int k = 0; k < NBLK_O; ++k) {
                const float vv = po[(size_t)k * 72];
                acc = isMin ? fminf(acc, vv) : (isMax ? fmaxf(acc, vv) : acc + vv);
            }
            sO[part][kind] = acc;
        }
        {
            const float* ps = partS + ((size_t)b * NBLK_S) * 72 + q;
            float acc = isMin ? INFINITY : (isMax ? -INFINITY : 0.f);
#pragma unroll
            for (int k = 0; k < NBLK_S; ++k) {
                const float vv = ps[(size_t)k * 72];
                acc = isMin ? fminf(acc, vv) : (isMax ? fmaxf(acc, vv) : acc + vv);
            }
            sS[part][kind] = acc;
        }
    }
    __syncthreads();

    const int ps = t >> 3;
    const int po = t & 7;

    // overlap[b, po]: bbox of smpl part po vs bbox of object part po (exact)
    const float* ssp = sS[po];
    const float* sop = sO[po];
    const float pcu = (ssp[0] + ssp[1]) * 0.5f;
    const float phu = (ssp[1] - ssp[0]) * 0.5f * 1.5f;
    const float pcw = (ssp[2] + ssp[3]) * 0.5f;
    const float phw = (ssp[3] - ssp[2]) * 0.5f * 1.5f;
    const float px0 = pcu - phu, px1 = pcu + phu;
    const float py0 = pcw - phw, py1 = pcw + phw;
    const float ocu = (sop[0] + sop[1]) * 0.5f;
    const float ohu = (sop[1] - sop[0]) * 0.5f * 1.5f;
    const float ocw = (sop[2] + sop[3]) * 0.5f;
    const float ohw = (sop[3] - sop[2]) * 0.5f * 1.5f;
    const float ox0 = ocu - ohu, ox1 = ocu + ohu;
    const float oy0 = ocw - ohw, oy1 = ocw + ohw;
    const bool ov = !((ox0 > px1) || (px0 > ox1) || (oy0 > py1) || (py0 > oy1));

    // z window: smpl part ps vs object part po (exact)
    const float a  = sS[ps][4];
    const float bm = sS[ps][5];
    const float c  = sO[po][4];
    const float d  = sO[po][5];
    const float gap = fminf(fabsf(c - bm), fabsf(a - d));
    const float zd = ((d >= a) && (bm >= c)) ? 0.f : gap;
    const bool m = ov && (zd < ZTH_);

    // pair mse of part means (K power of two -> division exact)
    const float ms0 = sS[ps][6] / (float)KS_;
    const float ms1 = sS[ps][7] / (float)KS_;
    const float ms2 = sS[ps][8] / (float)KS_;
    const float mo0 = sO[po][6] / (float)KO_;
    const float mo1 = sO[po][7] / (float)KO_;
    const float mo2 = sO[po][8] / (float)KO_;
    const float d0 = ms0 - mo0, d1 = ms1 - mo1, d2 = ms2 - mo2;
    const float pm = (d0 * d0 + d1 * d1 + d2 * d2) / 3.0f;

    float psum = m ? pm : 0.f;
    float pcnt = m ? 1.f : 0.f;
    psum = wredsum(psum);
    pcnt = wredsum(pcnt);
    if (t == 0) {
        pairPartial[(size_t)b * 2 + 0] = psum;
        pairPartial[(size_t)b * 2 + 1] = pcnt;
    }
}

// ---------------------------------------------------------------------------
// Kernel 4: loss_inter (bitwise-identical to round-1 means_li) + final reduce.
// ---------------------------------------------------------------------------
__global__ __launch_bounds__(256) void last_kernel(
        const float* __restrict__ sumS, const float* __restrict__ sumO,
        const float* __restrict__ pairPartial, float* __restrict__ out) {
    const int t = threadIdx.x;
    float d2 = 0.f;
#pragma unroll
    for (int c = 0; c < 3; ++c) {
        float ss = 0.f, so = 0.f;
#pragma unroll
        for (int k = 0; k < NBLK_S; ++k) ss += sumS[((size_t)t * NBLK_S + k) * 3 + c];
#pragma unroll
        for (int k = 0; k < NBLK_O; ++k) so += sumO[((size_t)t * NBLK_O + k) * 3 + c];
        const float ms = ss / (float)NS_;
        const float mo = so / (float)NO_;
        const float d = ms - mo;
        d2 += d * d;
    }
    float s = pairPartial[(size_t)t * 2 + 0];
    float c2 = pairPartial[(size_t)t * 2 + 1];
    __shared__ float rli[4], rs[4], rc[4];
    const float rl = wredsum(d2);
    const float ss2 = wredsum(s);
    const float cc = wredsum(c2);
    const int lane = t & 63, wv = t >> 6;
    if (lane == 0) { rli[wv] = rl; rs[wv] = ss2; rc[wv] = cc; }
    __syncthreads();
    if (t == 0) {
        const float tot = rli[0] + rli[1] + rli[2] + rli[3];
        out[0] = tot / (3.0f * (float)B_) / (float)B_;
        const float S = rs[0] + rs[1] + rs[2] + rs[3];
        const float C = rc[0] + rc[1] + rc[2] + rc[3];
        out[1] = (C > 0.f) ? (S / C) : 0.f;
    }
}

// ---------------------------------------------------------------------------
extern "C" void kernel_launch(void* const* d_in, const int* in_sizes, int n_in,
                              void* d_out, int out_size, void* d_ws, size_t ws_size,
                              hipStream_t stream) {
    const float* smpl = (const float*)d_in[0];
    const float* obj  = (const float*)d_in[1];
    const float* Ks   = (const float*)d_in[2];
    const int*   sidx = (const int*)d_in[3];
    const int*   oidx = (const int*)d_in[4];
    float* out = (float*)d_out;

    // workspace layout
    unsigned* cntO = (unsigned*)d_ws;                         // 65536 u32
    unsigned* cntS = cntO + 65536;                            // 10496 u32 (padded)
    float* sumO = (float*)(cntS + 10496);                     // 256*16*3 = 12288
    float* sumS = sumO + (size_t)B_ * NBLK_O * 3;             // 256*4*3  = 3072
    float* partO = sumS + (size_t)B_ * NBLK_S * 3;            // 256*16*72 = 294912
    float* partS = partO + (size_t)B_ * NBLK_O * 72;          // 256*4*72  = 73728
    float* pairP = partS + (size_t)B_ * NBLK_S * 72;          // 512

    hipMemsetAsync(cntO, 0, (65536 + 10496) * sizeof(unsigned), stream);
    scatter_counts_kernel<<<(P_ * KO_ + P_ * KS_ + 255) / 256, 256, 0, stream>>>(
        sidx, oidx, cntS, cntO);
    fused_stream_kernel<<<B_ * NBLK_O + B_ * NBLK_S, 256, 0, stream>>>(
        obj, smpl, cntO, cntS, Ks, partO, sumO, partS, sumS);
    finish_kernel<<<B_, 64, 0, stream>>>(partS, partO, pairP);
    last_kernel<<<1, 256, 0, stream>>>(sumS, sumO, pairP, out);
}

// Round 5
// 175.735 us; speedup vs baseline: 1.0451x; 1.0451x over previous
//
#include <hip/hip_runtime.h>
#include <math.h>

// PHOSA interaction loss, MI355X — gather-free formulation, spill-fixed v2.
// Part index lists are batch-independent: per-vertex part multiplicity
// (4-bit count x 8 parts packed in a u32) is built once; part statistics are
// computed in the SAME streaming pass as the batch sums.
// Round-5 change: amdgpu_waves_per_eu(2) raises the VGPR cap to 256/wave so
// the ~95 live values (72 accumulators + working set) fit in registers.
// Round 3 (default): 80 VGPR -> spills hidden in L2. Round 4 (launch_bounds
// (256,4)): 64 VGPR -> 139 MB scratch to HBM. Both ~190 us VALU-bound.
constexpr int B_   = 256;
constexpr int NS_  = 10475;
constexpr int NO_  = 65536;
constexpr int P_   = 8;
constexpr int KS_  = 1024;
constexpr int KO_  = 2048;
constexpr int NBLK_S = 4;    // blocks per batch, smpl stream
constexpr int NBLK_O = 16;   // blocks per batch, object stream
constexpr float EPS_ = 1e-9f;
constexpr float ZTH_ = 5.0f;

#define DEV_INLINE __device__ __forceinline__

DEV_INLINE float wredsum(float v) {
#pragma unroll
    for (int o = 32; o; o >>= 1) v += __shfl_down(v, o);
    return v;
}
DEV_INLINE float wredmin(float v) {
#pragma unroll
    for (int o = 32; o; o >>= 1) v = fminf(v, __shfl_down(v, o));
    return v;
}
DEV_INLINE float wredmax(float v) {
#pragma unroll
    for (int o = 32; o; o >>= 1) v = fmaxf(v, __shfl_down(v, o));
    return v;
}

// ---------------------------------------------------------------------------
// Kernel 1: scatter part multiplicities into per-vertex count tables.
// cnt[vertex] bits [4p, 4p+4) = number of times vertex appears in part p.
// ---------------------------------------------------------------------------
__global__ __launch_bounds__(256) void scatter_counts_kernel(
        const int* __restrict__ sidx, const int* __restrict__ oidx,
        unsigned* __restrict__ cntS, unsigned* __restrict__ cntO) {
    const int t = blockIdx.x * 256 + threadIdx.x;
    constexpr int TO = P_ * KO_;
    if (t < TO) {
        const int p = t / KO_;
        atomicAdd(&cntO[oidx[t]], 1u << (4 * p));
    } else if (t < TO + P_ * KS_) {
        const int u = t - TO;
        const int p = u / KS_;
        atomicAdd(&cntS[sidx[u]], 1u << (4 * p));
    }
}

// ---------------------------------------------------------------------------
// Kernel 2: fused stream. Blocks [0, B*NBLK_O) stream object, rest smpl.
// Per block: partial batch xyz sums (bitwise-identical order to round-1 path)
// + per-part {umin,umax,wmin,wmax,zmin,zmax,sx,sy,sz} partials.
// Partial layout per (b,blk): 72 floats, q = kind*8 + part.
// amdgpu_waves_per_eu(2): VGPR cap 256 -> all 72 accumulators in registers.
// ---------------------------------------------------------------------------
__global__ __launch_bounds__(256)
__attribute__((amdgpu_waves_per_eu(2)))
void fused_stream_kernel(
        const float* __restrict__ obj, const float* __restrict__ smpl,
        const unsigned* __restrict__ cntO, const unsigned* __restrict__ cntS,
        const float* __restrict__ Ks,
        float* __restrict__ partO, float* __restrict__ sumO,
        float* __restrict__ partS, float* __restrict__ sumS) {
    int gid = blockIdx.x;
    const float* v; const unsigned* cnt; int N, NBLK, b, blk;
    float* part; float* sums;
    if (gid < B_ * NBLK_O) {
        v = obj; cnt = cntO; N = NO_; NBLK = NBLK_O;
        b = gid / NBLK_O; blk = gid % NBLK_O; part = partO; sums = sumO;
    } else {
        gid -= B_ * NBLK_O;
        v = smpl; cnt = cntS; N = NS_; NBLK = NBLK_S;
        b = gid / NBLK_S; blk = gid % NBLK_S; part = partS; sums = sumS;
    }
    const int chunk = (N + NBLK - 1) / NBLK;
    const int s0 = blk * chunk;
    const int e0 = min(N, s0 + chunk);
    const float* base = v + (size_t)b * N * 3;
    const float fx = Ks[b * 9 + 0];
    const float cx = Ks[b * 9 + 2];
    const float fy = Ks[b * 9 + 4];
    const float cy = Ks[b * 9 + 5];

    float sx = 0.f, sy = 0.f, sz = 0.f;
    float umin[8], umax[8], wmin[8], wmax[8], zmn[8], zmx[8], psx[8], psy[8], psz[8];
#pragma unroll
    for (int q = 0; q < 8; ++q) {
        umin[q] = INFINITY; umax[q] = -INFINITY;
        wmin[q] = INFINITY; wmax[q] = -INFINITY;
        zmn[q]  = INFINITY; zmx[q]  = -INFINITY;
        psx[q] = 0.f; psy[q] = 0.f; psz[q] = 0.f;
    }

    for (int i = s0 + (int)threadIdx.x; i < e0; i += 256) {
        const float* p = base + (size_t)i * 3;
        const float x = p[0], y = p[1], z = p[2];
        sx += x; sy += y; sz += z;
        const unsigned c = cnt[i];
        float u, w;
        {
#pragma clang fp contract(off)
            const float zd = z + EPS_;
            const float x_ = x / zd;
            const float y_ = (-y) / zd;
            u = fx * x_ + cx;
            w = 1.0f - (fy * y_ + cy);
            u = 2.0f * (u - 0.5f);
            w = 2.0f * (w - 0.5f);
        }
#pragma unroll
        for (int q = 0; q < 8; ++q) {
            const unsigned cq = (c >> (4 * q)) & 15u;
            const float fc = (float)cq;
            const bool a = cq != 0u;
            umin[q] = fminf(umin[q], a ? u :  INFINITY);
            umax[q] = fmaxf(umax[q], a ? u : -INFINITY);
            wmin[q] = fminf(wmin[q], a ? w :  INFINITY);
            wmax[q] = fmaxf(wmax[q], a ? w : -INFINITY);
            zmn[q]  = fminf(zmn[q],  a ? z :  INFINITY);
            zmx[q]  = fmaxf(zmx[q],  a ? z : -INFINITY);
            psx[q] = fmaf(fc, x, psx[q]);
            psy[q] = fmaf(fc, y, psy[q]);
            psz[q] = fmaf(fc, z, psz[q]);
        }
    }

    // wave reductions
    sx = wredsum(sx); sy = wredsum(sy); sz = wredsum(sz);
#pragma unroll
    for (int q = 0; q < 8; ++q) {
        umin[q] = wredmin(umin[q]); umax[q] = wredmax(umax[q]);
        wmin[q] = wredmin(wmin[q]); wmax[q] = wredmax(wmax[q]);
        zmn[q]  = wredmin(zmn[q]);  zmx[q]  = wredmax(zmx[q]);
        psx[q]  = wredsum(psx[q]);  psy[q]  = wredsum(psy[q]);
        psz[q]  = wredsum(psz[q]);
    }
    __shared__ float red[4][76];
    const int lane = threadIdx.x & 63, wv = threadIdx.x >> 6;
    if (lane == 0) {
        red[wv][0] = sx; red[wv][1] = sy; red[wv][2] = sz;
#pragma unroll
        for (int q = 0; q < 8; ++q) {
            red[wv][3 + 0 * 8 + q] = umin[q];
            red[wv][3 + 1 * 8 + q] = umax[q];
            red[wv][3 + 2 * 8 + q] = wmin[q];
            red[wv][3 + 3 * 8 + q] = wmax[q];
            red[wv][3 + 4 * 8 + q] = zmn[q];
            red[wv][3 + 5 * 8 + q] = zmx[q];
            red[wv][3 + 6 * 8 + q] = psx[q];
            red[wv][3 + 7 * 8 + q] = psy[q];
            red[wv][3 + 8 * 8 + q] = psz[q];
        }
    }
    __syncthreads();
    const int t = threadIdx.x;
    if (t < 75) {
        const float a0 = red[0][t], a1 = red[1][t], a2 = red[2][t], a3 = red[3][t];
        if (t < 3) {
            // same combine order as round-1 batch_sum -> loss_inter bitwise identical
            sums[((size_t)b * NBLK + blk) * 3 + t] = a0 + a1 + a2 + a3;
        } else {
            const int kind = (t - 3) >> 3;
            float r;
            if (kind == 0 || kind == 2 || kind == 4)
                r = fminf(fminf(a0, a1), fminf(a2, a3));
            else if (kind == 1 || kind == 3 || kind == 5)
                r = fmaxf(fmaxf(a0, a1), fmaxf(a2, a3));
            else
                r = a0 + a1 + a2 + a3;
            part[((size_t)b * NBLK + blk) * 72 + (t - 3)] = r;
        }
    }
}

// ---------------------------------------------------------------------------
// Kernel 3: per-batch finish — combine stream partials into 8x9 stats per
// tensor, then the 8x8 pair mask/mse. One block (64 thr) per batch.
// ---------------------------------------------------------------------------
__global__ __launch_bounds__(64) void finish_kernel(
        const float* __restrict__ partS, const float* __restrict__ partO,
        float* __restrict__ pairPartial) {
#pragma clang fp contract(off)
    const int b = blockIdx.x;
    const int t = threadIdx.x;
    __shared__ float sS[P_][9];
    __shared__ float sO[P_][9];
    for (int q = t; q < 72; q += 64) {
        const int kind = q >> 3, part = q & 7;
        const bool isMin = (kind == 0 || kind == 2 || kind == 4);
        const bool isMax = (kind == 1 || kind == 3 || kind == 5);
        {
            const float* po = partO + ((size_t)b * NBLK_O) * 72 + q;
            float acc = isMin ? INFINITY : (isMax ? -INFINITY : 0.f);
#pragma unroll
            for (int k = 0; k < NBLK_O; ++k) {
                const float vv = po[(size_t)k * 72];
                acc = isMin ? fminf(acc, vv) : (isMax ? fmaxf(acc, vv) : acc + vv);
            }
            sO[part][kind] = acc;
        }
        {
            const float* ps = partS + ((size_t)b * NBLK_S) * 72 + q;
            float acc = isMin ? INFINITY : (isMax ? -INFINITY : 0.f);
#pragma unroll
            for (int k = 0; k < NBLK_S; ++k) {
                const float vv = ps[(size_t)k * 72];
                acc = isMin ? fminf(acc, vv) : (isMax ? fmaxf(acc, vv) : acc + vv);
            }
            sS[part][kind] = acc;
        }
    }
    __syncthreads();

    const int ps = t >> 3;
    const int po = t & 7;

    // overlap[b, po]: bbox of smpl part po vs bbox of object part po (exact)
    const float* ssp = sS[po];
    const float* sop = sO[po];
    const float pcu = (ssp[0] + ssp[1]) * 0.5f;
    const float phu = (ssp[1] - ssp[0]) * 0.5f * 1.5f;
    const float pcw = (ssp[2] + ssp[3]) * 0.5f;
    const float phw = (ssp[3] - ssp[2]) * 0.5f * 1.5f;
    const float px0 = pcu - phu, px1 = pcu + phu;
    const float py0 = pcw - phw, py1 = pcw + phw;
    const float ocu = (sop[0] + sop[1]) * 0.5f;
    const float ohu = (sop[1] - sop[0]) * 0.5f * 1.5f;
    const float ocw = (sop[2] + sop[3]) * 0.5f;
    const float ohw = (sop[3] - sop[2]) * 0.5f * 1.5f;
    const float ox0 = ocu - ohu, ox1 = ocu + ohu;
    const float oy0 = ocw - ohw, oy1 = ocw + ohw;
    const bool ov = !((ox0 > px1) || (px0 > ox1) || (oy0 > py1) || (py0 > oy1));

    // z window: smpl part ps vs object part po (exact)
    const float a  = sS[ps][4];
    const float bm = sS[ps][5];
    const float c  = sO[po][4];
    const float d  = sO[po][5];
    const float gap = fminf(fabsf(c - bm), fabsf(a - d));
    const float zd = ((d >= a) && (bm >= c)) ? 0.f : gap;
    const bool m = ov && (zd < ZTH_);

    // pair mse of part means (K power of two -> division exact)
    const float ms0 = sS[ps][6] / (float)KS_;
    const float ms1 = sS[ps][7] / (float)KS_;
    const float ms2 = sS[ps][8] / (float)KS_;
    const float mo0 = sO[po][6] / (float)KO_;
    const float mo1 = sO[po][7] / (float)KO_;
    const float mo2 = sO[po][8] / (float)KO_;
    const float d0 = ms0 - mo0, d1 = ms1 - mo1, d2 = ms2 - mo2;
    const float pm = (d0 * d0 + d1 * d1 + d2 * d2) / 3.0f;

    float psum = m ? pm : 0.f;
    float pcnt = m ? 1.f : 0.f;
    psum = wredsum(psum);
    pcnt = wredsum(pcnt);
    if (t == 0) {
        pairPartial[(size_t)b * 2 + 0] = psum;
        pairPartial[(size_t)b * 2 + 1] = pcnt;
    }
}

// ---------------------------------------------------------------------------
// Kernel 4: loss_inter (bitwise-identical to round-1 means_li) + final reduce.
// ---------------------------------------------------------------------------
__global__ __launch_bounds__(256) void last_kernel(
        const float* __restrict__ sumS, const float* __restrict__ sumO,
        const float* __restrict__ pairPartial, float* __restrict__ out) {
    const int t = threadIdx.x;
    float d2 = 0.f;
#pragma unroll
    for (int c = 0; c < 3; ++c) {
        float ss = 0.f, so = 0.f;
#pragma unroll
        for (int k = 0; k < NBLK_S; ++k) ss += sumS[((size_t)t * NBLK_S + k) * 3 + c];
#pragma unroll
        for (int k = 0; k < NBLK_O; ++k) so += sumO[((size_t)t * NBLK_O + k) * 3 + c];
        const float ms = ss / (float)NS_;
        const float mo = so / (float)NO_;
        const float d = ms - mo;
        d2 += d * d;
    }
    float s = pairPartial[(size_t)t * 2 + 0];
    float c2 = pairPartial[(size_t)t * 2 + 1];
    __shared__ float rli[4], rs[4], rc[4];
    const float rl = wredsum(d2);
    const float ss2 = wredsum(s);
    const float cc = wredsum(c2);
    const int lane = t & 63, wv = t >> 6;
    if (lane == 0) { rli[wv] = rl; rs[wv] = ss2; rc[wv] = cc; }
    __syncthreads();
    if (t == 0) {
        const float tot = rli[0] + rli[1] + rli[2] + rli[3];
        out[0] = tot / (3.0f * (float)B_) / (float)B_;
        const float S = rs[0] + rs[1] + rs[2] + rs[3];
        const float C = rc[0] + rc[1] + rc[2] + rc[3];
        out[1] = (C > 0.f) ? (S / C) : 0.f;
    }
}

// ---------------------------------------------------------------------------
extern "C" void kernel_launch(void* const* d_in, const int* in_sizes, int n_in,
                              void* d_out, int out_size, void* d_ws, size_t ws_size,
                              hipStream_t stream) {
    const float* smpl = (const float*)d_in[0];
    const float* obj  = (const float*)d_in[1];
    const float* Ks   = (const float*)d_in[2];
    const int*   sidx = (const int*)d_in[3];
    const int*   oidx = (const int*)d_in[4];
    float* out = (float*)d_out;

    // workspace layout
    unsigned* cntO = (unsigned*)d_ws;                         // 65536 u32
    unsigned* cntS = cntO + 65536;                            // 10496 u32 (padded)
    float* sumO = (float*)(cntS + 10496);                     // 256*16*3 = 12288
    float* sumS = sumO + (size_t)B_ * NBLK_O * 3;             // 256*4*3  = 3072
    float* partO = sumS + (size_t)B_ * NBLK_S * 3;            // 256*16*72 = 294912
    float* partS = partO + (size_t)B_ * NBLK_O * 72;          // 256*4*72  = 73728
    float* pairP = partS + (size_t)B_ * NBLK_S * 72;          // 512

    hipMemsetAsync(cntO, 0, (65536 + 10496) * sizeof(unsigned), stream);
    scatter_counts_kernel<<<(P_ * KO_ + P_ * KS_ + 255) / 256, 256, 0, stream>>>(
        sidx, oidx, cntS, cntO);
    fused_stream_kernel<<<B_ * NBLK_O + B_ * NBLK_S, 256, 0, stream>>>(
        obj, smpl, cntO, cntS, Ks, partO, sumO, partS, sumS);
    finish_kernel<<<B_, 64, 0, stream>>>(partS, partO, pairP);
    last_kernel<<<1, 256, 0, stream>>>(sumS, sumO, pairP, out);
}

// Round 6
// 69.852 us; speedup vs baseline: 2.6292x; 2.5158x over previous
//
#include <hip/hip_runtime.h>
#include <math.h>

// PHOSA interaction loss, MI355X — round 6: single fused phase-1 kernel.
// batch_sum (HBM-bound stream) and part_stats (L1/latency-bound gather) are
// data-independent, so they run as block-roles of ONE kernel and overlap.
// Block mapping pins ALL work of batch b to XCD b&7 so the stream fills the
// per-XCD L2 with batch b's vertex window and the gathers for the same batch
// hit that L2. Math bodies are verbatim from round 2 (absmax 0.0 proven).
constexpr int B_   = 256;
constexpr int NS_  = 10475;
constexpr int NO_  = 65536;
constexpr int P_   = 8;
constexpr int KS_  = 1024;
constexpr int KO_  = 2048;
constexpr int NBLK_S = 4;    // stream blocks per batch, smpl
constexpr int NBLK_O = 16;   // stream blocks per batch, object
constexpr float EPS_ = 1e-9f;
constexpr float ZTH_ = 5.0f;

// per-batch work units: 16 objsum + 8 objgather + 4 smplsum + 8 smplgather
constexpr int UNITS_PER_B = NBLK_O + P_ + NBLK_S + P_;   // 36
constexpr int NXCD = 8;
constexpr int B_PER_XCD = B_ / NXCD;                     // 32

#define DEV_INLINE __device__ __forceinline__

DEV_INLINE float wredsum(float v) {
#pragma unroll
    for (int o = 32; o; o >>= 1) v += __shfl_down(v, o);
    return v;
}
DEV_INLINE float wredmin(float v) {
#pragma unroll
    for (int o = 32; o; o >>= 1) v = fminf(v, __shfl_down(v, o));
    return v;
}
DEV_INLINE float wredmax(float v) {
#pragma unroll
    for (int o = 32; o; o >>= 1) v = fmaxf(v, __shfl_down(v, o));
    return v;
}

// ---------------------------------------------------------------------------
// Role body: per-batch component partial sums (verbatim round-1/2 batch_sum).
// ---------------------------------------------------------------------------
template <int N, int NBLK>
DEV_INLINE void batch_sum_body(const float* __restrict__ v, int b, int blk,
                               float* __restrict__ out) {
    const int chunk = (N + NBLK - 1) / NBLK;
    const int s = blk * chunk;
    const int e = min(N, s + chunk);
    const float* base = v + (size_t)b * N * 3;
    float sx = 0.f, sy = 0.f, sz = 0.f;
    for (int i = s + (int)threadIdx.x; i < e; i += 256) {
        const float* p = base + (size_t)i * 3;
        sx += p[0];
        sy += p[1];
        sz += p[2];
    }
    __shared__ float red[3][4];
    float r0 = wredsum(sx), r1 = wredsum(sy), r2 = wredsum(sz);
    const int lane = threadIdx.x & 63, wv = threadIdx.x >> 6;
    if (lane == 0) { red[0][wv] = r0; red[1][wv] = r1; red[2][wv] = r2; }
    __syncthreads();
    if (threadIdx.x == 0) {
        float* o = out + ((size_t)b * NBLK + blk) * 3;
        o[0] = red[0][0] + red[0][1] + red[0][2] + red[0][3];
        o[1] = red[1][0] + red[1][1] + red[1][2] + red[1][3];
        o[2] = red[2][0] + red[2][1] + red[2][2] + red[2][3];
    }
}

// ---------------------------------------------------------------------------
// Role body: per-(batch,part) gather statistics (verbatim round-2).
// out[(b*P+p)*9 + q], q: 0 umin 1 umax 2 wmin 3 wmax 4 zmin 5 zmax 6 sx 7 sy 8 sz
// ---------------------------------------------------------------------------
template <int N, int K>
DEV_INLINE void part_stats_body(const float* __restrict__ v,
                                const int* __restrict__ pidx,
                                const float* __restrict__ Ks, int b, int p,
                                float* __restrict__ out) {
    const float fx = Ks[b * 9 + 0];
    const float cx = Ks[b * 9 + 2];
    const float fy = Ks[b * 9 + 4];
    const float cy = Ks[b * 9 + 5];
    const float* base = v + (size_t)b * N * 3;
    const int* idx = pidx + (size_t)p * K;

    float umin = INFINITY, umax = -INFINITY, wmin = INFINITY, wmax = -INFINITY;
    float zmin = INFINITY, zmax = -INFINITY;
    float sx = 0.f, sy = 0.f, sz = 0.f;

    constexpr int ITER = K / 256;
    int ids[ITER];
#pragma unroll
    for (int j = 0; j < ITER; ++j) ids[j] = idx[threadIdx.x + j * 256];

#pragma unroll
    for (int j = 0; j < ITER; ++j) {
        const float* vp = base + (size_t)ids[j] * 3;
        const float x = vp[0], y = vp[1], z = vp[2];
        sx += x; sy += y; sz += z;
        zmin = fminf(zmin, z); zmax = fmaxf(zmax, z);
        float u, w;
        {
#pragma clang fp contract(off)
            const float zd = z + EPS_;
            const float x_ = x / zd;
            const float y_ = (-y) / zd;
            u = fx * x_ + cx;
            w = 1.0f - (fy * y_ + cy);
            u = 2.0f * (u - 0.5f);
            w = 2.0f * (w - 0.5f);
        }
        umin = fminf(umin, u); umax = fmaxf(umax, u);
        wmin = fminf(wmin, w); wmax = fmaxf(wmax, w);
    }

    __shared__ float red[4][9];
    float r[9];
    r[0] = wredmin(umin); r[1] = wredmax(umax);
    r[2] = wredmin(wmin); r[3] = wredmax(wmax);
    r[4] = wredmin(zmin); r[5] = wredmax(zmax);
    r[6] = wredsum(sx);   r[7] = wredsum(sy); r[8] = wredsum(sz);
    const int lane = threadIdx.x & 63, wv = threadIdx.x >> 6;
    if (lane == 0) {
#pragma unroll
        for (int q = 0; q < 9; ++q) red[wv][q] = r[q];
    }
    __syncthreads();
    if (threadIdx.x == 0) {
        float* o = out + ((size_t)b * P_ + p) * 9;
        o[0] = fminf(fminf(red[0][0], red[1][0]), fminf(red[2][0], red[3][0]));
        o[1] = fmaxf(fmaxf(red[0][1], red[1][1]), fmaxf(red[2][1], red[3][1]));
        o[2] = fminf(fminf(red[0][2], red[1][2]), fminf(red[2][2], red[3][2]));
        o[3] = fmaxf(fmaxf(red[0][3], red[1][3]), fmaxf(red[2][3], red[3][3]));
        o[4] = fminf(fminf(red[0][4], red[1][4]), fminf(red[2][4], red[3][4]));
        o[5] = fmaxf(fmaxf(red[0][5], red[1][5]), fmaxf(red[2][5], red[3][5]));
        o[6] = red[0][6] + red[1][6] + red[2][6] + red[3][6];
        o[7] = red[0][7] + red[1][7] + red[2][7] + red[3][7];
        o[8] = red[0][8] + red[1][8] + red[2][8] + red[3][8];
    }
}

// ---------------------------------------------------------------------------
// Phase 1: all independent heavy work in one launch, roles by blockIdx.
// gid = blockIdx.x; xcd = gid&7; unit = gid>>3; b = (unit/36)*8 + xcd.
// role = unit%36: [0,16) objsum | [16,24) objgather | [24,28) smplsum
//                 | [28,36) smplgather.
// ---------------------------------------------------------------------------
__global__ __launch_bounds__(256) void phase1_kernel(
        const float* __restrict__ obj, const float* __restrict__ smpl,
        const float* __restrict__ Ks,
        const int* __restrict__ sidx, const int* __restrict__ oidx,
        float* __restrict__ sumO, float* __restrict__ sumS,
        float* __restrict__ statsO, float* __restrict__ statsS) {
    const int gid = blockIdx.x;
    const int xcd = gid & (NXCD - 1);
    const int unit = gid >> 3;
    const int b = (unit / UNITS_PER_B) * NXCD + xcd;
    const int role = unit % UNITS_PER_B;
    if (role < NBLK_O) {
        batch_sum_body<NO_, NBLK_O>(obj, b, role, sumO);
    } else if (role < NBLK_O + P_) {
        part_stats_body<NO_, KO_>(obj, oidx, Ks, b, role - NBLK_O, statsO);
    } else if (role < NBLK_O + P_ + NBLK_S) {
        batch_sum_body<NS_, NBLK_S>(smpl, b, role - (NBLK_O + P_), sumS);
    } else {
        part_stats_body<NS_, KS_>(smpl, sidx, Ks, b, role - (NBLK_O + P_ + NBLK_S), statsS);
    }
}

// ---------------------------------------------------------------------------
// Kernel D: per-batch pair masking + partial sums (verbatim round-2).
// ---------------------------------------------------------------------------
__global__ __launch_bounds__(64) void pair_kernel(
        const float* __restrict__ statsS, const float* __restrict__ statsO,
        float* __restrict__ partial) {
#pragma clang fp contract(off)
    const int b = blockIdx.x;
    __shared__ float sS[P_][9];
    __shared__ float sO[P_][9];
    const int t = threadIdx.x;
    for (int i = t; i < 2 * P_ * 9; i += 64) {
        if (i < P_ * 9) sS[i / 9][i % 9] = statsS[(size_t)b * P_ * 9 + i];
        else {
            const int u = i - P_ * 9;
            sO[u / 9][u % 9] = statsO[(size_t)b * P_ * 9 + u];
        }
    }
    __syncthreads();

    const int ps = t >> 3;
    const int po = t & 7;

    const float* ssp = sS[po];
    const float* sop = sO[po];
    const float pcu = (ssp[0] + ssp[1]) * 0.5f;
    const float phu = (ssp[1] - ssp[0]) * 0.5f * 1.5f;
    const float pcw = (ssp[2] + ssp[3]) * 0.5f;
    const float phw = (ssp[3] - ssp[2]) * 0.5f * 1.5f;
    const float px0 = pcu - phu, px1 = pcu + phu;
    const float py0 = pcw - phw, py1 = pcw + phw;
    const float ocu = (sop[0] + sop[1]) * 0.5f;
    const float ohu = (sop[1] - sop[0]) * 0.5f * 1.5f;
    const float ocw = (sop[2] + sop[3]) * 0.5f;
    const float ohw = (sop[3] - sop[2]) * 0.5f * 1.5f;
    const float ox0 = ocu - ohu, ox1 = ocu + ohu;
    const float oy0 = ocw - ohw, oy1 = ocw + ohw;
    const bool ov = !((ox0 > px1) || (px0 > ox1) || (oy0 > py1) || (py0 > oy1));

    const float a  = sS[ps][4];
    const float bm = sS[ps][5];
    const float c  = sO[po][4];
    const float d  = sO[po][5];
    const float gap = fminf(fabsf(c - bm), fabsf(a - d));
    const float zd = ((d >= a) && (bm >= c)) ? 0.f : gap;
    const bool m = ov && (zd < ZTH_);

    const float ms0 = sS[ps][6] / (float)KS_;
    const float ms1 = sS[ps][7] / (float)KS_;
    const float ms2 = sS[ps][8] / (float)KS_;
    const float mo0 = sO[po][6] / (float)KO_;
    const float mo1 = sO[po][7] / (float)KO_;
    const float mo2 = sO[po][8] / (float)KO_;
    const float d0 = ms0 - mo0, d1 = ms1 - mo1, d2 = ms2 - mo2;
    const float pm = (d0 * d0 + d1 * d1 + d2 * d2) / 3.0f;

    float psum = m ? pm : 0.f;
    float pcnt = m ? 1.f : 0.f;
    psum = wredsum(psum);
    pcnt = wredsum(pcnt);
    if (t == 0) {
        partial[(size_t)b * 2 + 0] = psum;
        partial[(size_t)b * 2 + 1] = pcnt;
    }
}

// ---------------------------------------------------------------------------
// Kernel E: loss_inter + final reduce (verbatim round-5 last_kernel).
// ---------------------------------------------------------------------------
__global__ __launch_bounds__(256) void last_kernel(
        const float* __restrict__ sumS, const float* __restrict__ sumO,
        const float* __restrict__ pairPartial, float* __restrict__ out) {
    const int t = threadIdx.x;
    float d2 = 0.f;
#pragma unroll
    for (int c = 0; c < 3; ++c) {
        float ss = 0.f, so = 0.f;
#pragma unroll
        for (int k = 0; k < NBLK_S; ++k) ss += sumS[((size_t)t * NBLK_S + k) * 3 + c];
#pragma unroll
        for (int k = 0; k < NBLK_O; ++k) so += sumO[((size_t)t * NBLK_O + k) * 3 + c];
        const float ms = ss / (float)NS_;
        const float mo = so / (float)NO_;
        const float d = ms - mo;
        d2 += d * d;
    }
    float s = pairPartial[(size_t)t * 2 + 0];
    float c2 = pairPartial[(size_t)t * 2 + 1];
    __shared__ float rli[4], rs[4], rc[4];
    const float rl = wredsum(d2);
    const float ss2 = wredsum(s);
    const float cc = wredsum(c2);
    const int lane = t & 63, wv = t >> 6;
    if (lane == 0) { rli[wv] = rl; rs[wv] = ss2; rc[wv] = cc; }
    __syncthreads();
    if (t == 0) {
        const float tot = rli[0] + rli[1] + rli[2] + rli[3];
        out[0] = tot / (3.0f * (float)B_) / (float)B_;
        const float S = rs[0] + rs[1] + rs[2] + rs[3];
        const float C = rc[0] + rc[1] + rc[2] + rc[3];
        out[1] = (C > 0.f) ? (S / C) : 0.f;
    }
}

// ---------------------------------------------------------------------------
extern "C" void kernel_launch(void* const* d_in, const int* in_sizes, int n_in,
                              void* d_out, int out_size, void* d_ws, size_t ws_size,
                              hipStream_t stream) {
    const float* smpl = (const float*)d_in[0];
    const float* obj  = (const float*)d_in[1];
    const float* Ks   = (const float*)d_in[2];
    const int*   sidx = (const int*)d_in[3];
    const int*   oidx = (const int*)d_in[4];
    float* out = (float*)d_out;

    float* w = (float*)d_ws;
    float* sumO   = w;                                 // 256*16*3 = 12288
    float* sumS   = sumO + (size_t)B_ * NBLK_O * 3;    // 256*4*3  = 3072
    float* statsS = sumS + (size_t)B_ * NBLK_S * 3;    // 256*8*9  = 18432
    float* statsO = statsS + (size_t)B_ * P_ * 9;      // 256*8*9  = 18432
    float* pairP  = statsO + (size_t)B_ * P_ * 9;      // 512

    phase1_kernel<<<B_ * UNITS_PER_B, 256, 0, stream>>>(
        obj, smpl, Ks, sidx, oidx, sumO, sumS, statsO, statsS);
    pair_kernel<<<B_, 64, 0, stream>>>(statsS, statsO, pairP);
    last_kernel<<<1, 256, 0, stream>>>(sumS, sumO, pairP, out);
}